// Round 11
// baseline (1173.596 us; speedup 1.0000x reference)
//
#include <hip/hip_runtime.h>

#define BB 512
#define TT 1024
#define DX 32
#define DZ 64
#define DY 256
#define ALPHA 0.125f
#define HP 36  // hid chunk stride: 32 floats + 4 pad

typedef float v2f __attribute__((ext_vector_type(2)));

// Packed dual-FP32 FMA (full-rate on gfx950).
__device__ __forceinline__ v2f pk_fma(v2f a, v2f b, v2f c) {
    asm("v_pk_fma_f32 %0, %1, %2, %0" : "+v"(c) : "v"(a), "v"(b));
    return c;
}
// DPP add: x + dpp_permuted(x). 0xB1 xor1 | 0x4E xor2 | 0x141 row_half_mirror.
template<int CTRL>
__device__ __forceinline__ float dpp_add(float x) {
    int p = __builtin_amdgcn_update_dpp(0, __float_as_int(x), CTRL, 0xF, 0xF, true);
    return x + __int_as_float(p);
}
// LDS-only barrier (no vmcnt drain; proven safe in R9).
__device__ __forceinline__ void lds_barrier() {
    __builtin_amdgcn_sched_barrier(0);
    asm volatile("s_waitcnt lgkmcnt(0)" ::: "memory");
    __builtin_amdgcn_s_barrier();
    __builtin_amdgcn_sched_barrier(0);
}

// R11: TWO batches per block, software-pipelined in ANTI-PHASE.
// Diagnosis of the 1930cy/step invariance (R0-R10): the 2 blocks/CU convoy
// into alternating phases at their barriers, so the two exchange chains ADD
// (~2x730cy) instead of hiding. Fix: fuse the two chains into ONE block and
// pipeline them internally -- each barrier window runs m2(batch A)+update
// alongside m1(batch B): two independent dep-chains per window, so each
// batch's LDS-turnaround latency hides under the OTHER batch's compute
// within the same wave. Buffer access per window is disjoint
// (W1: hid0.R zf0.W zf1.R hid1.W | W2: hid1.R zf1.W zf0.R hid0.W), so one
// barrier per window suffices. 2-step X prefetch keeps HBM misses (~900cy)
// off the chain at 1 block/CU (R2's failure mode).
// Grid: 256 blocks x 512 thr -> 1 block/CU, 2 waves/SIMD.
// m1: thread (y=tid>>1, h=tid&1): hidden row y over z-chunk 32h..+31; xor1.
// m2: thread (z=tid>>3, oct=tid&7): latent row z over y-chunk 32*oct..+31;
//     xor1+xor2+half_mirror; update replicated per oct-group, oct==0 stores.
__global__ __launch_bounds__(512)
__attribute__((amdgpu_waves_per_eu(2, 2)))
void plrnn_scan(const float* __restrict__ X, const float* __restrict__ A,
                const float* __restrict__ W1, const float* __restrict__ W2,
                const float* __restrict__ h1, const float* __restrict__ h2,
                float* __restrict__ out) {
    const int bb  = blockIdx.x * 2;
    const int tid = threadIdx.x;

    const int y   = tid >> 1;      // m1 output row 0..255
    const int h   = tid & 1;       // m1 z-chunk
    const int z   = tid >> 3;      // m2 output row 0..63
    const int oct = tid & 7;       // m2 y-chunk
    const int wv  = tid >> 6;      // wave id 0..7

    __shared__ float zf_s[2][DZ];
    __shared__ float hid_s[2][8 * HP];

    // ---- one-time: weight tiles (shared by both batches) ----
    v2f w2p[16];   // pairs of W2[y][32h + ...]
    v2f w1p[16];   // pairs of W1[z][32*oct + ...]
#pragma unroll
    for (int j = 0; j < 8; ++j) {
        float4 t2 = *(const float4*)&W2[y * DZ + 32 * h + 4 * j];
        float4 t1 = *(const float4*)&W1[z * DY + 32 * oct + 4 * j];
        w2p[2 * j]     = v2f{t2.x, t2.y};
        w2p[2 * j + 1] = v2f{t2.z, t2.w};
        w1p[2 * j]     = v2f{t1.x, t1.y};
        w1p[2 * j + 1] = v2f{t1.z, t1.w};
    }
    const float h2i = (h == 0) ? h2[y] : 0.0f;
    const float h1i = (oct == 0) ? h1[z] : 0.0f;
    const float Ar  = A[z];
    const bool  zdx = (z < DX);    // wave-uniform (waves 0-3)

    const float* Xb0 = X + (size_t)bb * TT * DX;
    const float* Xb1 = Xb0 + (size_t)TT * DX;
    float* op0 = out + (size_t)bb * TT * DX + z;
    float* op1 = op0 + (size_t)TT * DX;
    const float NANF = __int_as_float(0x7fc00000);

    // ---- zf_0 = x0 (non-NaN) on first DX dims, else 0 ----
    float zf0 = 0.f, zf1 = 0.f;
    if (zdx) {
        float xa = Xb0[z], xb = Xb1[z];
        zf0 = (xa == xa) ? xa : 0.f;
        zf1 = (xb == xb) ? xb : 0.f;
    }
    if (oct == 0) { zf_s[0][z] = zf0; zf_s[1][z] = zf1; }
    __syncthreads();

    const int hidx = wv * HP + (y & 31);   // m1 write slot (h==0 lanes)

    // m1-role: hid_s[sel] = relu(W2 @ zf_s[sel] + h2)
    auto m1_role = [&](const int sel) {
        float4 zl4[8];
        {
            const float4* zp = (const float4*)(&zf_s[sel][32 * h]);
#pragma unroll
            for (int j = 0; j < 8; ++j) zl4[j] = zp[j];
        }
        v2f accA = {h2i, 0.f}, accB = {0.f, 0.f};
#pragma unroll
        for (int j = 0; j < 8; ++j) {
            accA = pk_fma(w2p[2 * j],     v2f{zl4[j].x, zl4[j].y}, accA);
            accB = pk_fma(w2p[2 * j + 1], v2f{zl4[j].z, zl4[j].w}, accB);
        }
        float d1 = (accA[0] + accB[0]) + (accA[1] + accB[1]);
        d1 = dpp_add<0xB1>(d1);
        if (h == 0) hid_s[sel][hidx] = fmaxf(d1, 0.0f);
    };

    // m2-role + fused update for batch 'sel'; xn = next forcing (NaN skips)
    auto m2_role = [&](const int sel, float& zfr, const float xn, float* opz) {
        float4 hl4[8];
        {
            const float4* hp = (const float4*)(&hid_s[sel][HP * oct]);
#pragma unroll
            for (int j = 0; j < 8; ++j) hl4[j] = hp[j];
        }
        v2f acA = {h1i, 0.f}, acB = {0.f, 0.f};
#pragma unroll
        for (int j = 0; j < 8; ++j) {
            acA = pk_fma(w1p[2 * j],     v2f{hl4[j].x, hl4[j].y}, acA);
            acB = pk_fma(w1p[2 * j + 1], v2f{hl4[j].z, hl4[j].w}, acB);
        }
        float d2 = (acA[0] + acB[0]) + (acA[1] + acB[1]);
        d2 = dpp_add<0xB1>(d2);
        d2 = dpp_add<0x4E>(d2);
        d2 = dpp_add<0x141>(d2);

        float zn = fmaf(Ar, zfr, d2);
        if (zdx) {
            if (oct == 0) *opz = zn;
            zfr = (xn == xn) ? fmaf(ALPHA, xn, 0.875f * zn) : zn;
        } else {
            zfr = zn;
        }
        if (oct == 0) zf_s[sel][z] = zfr;
    };

    // ---- X prefetch: q = X[t+1][z], 2-step-deep rotation ----
    const float* xp0 = Xb0 + z + DX;
    const float* xp1 = Xb1 + z + DX;
    float q0 = NANF, q1 = NANF;
    if (zdx) { q0 = xp0[0]; q1 = xp1[0]; }

    // prologue: fill hid0 for batch0's first m2
    m1_role(0);
    lds_barrier();

    for (int t = 0; t < TT; ++t) {
        // issue X[t+2] loads now (~2 windows of slack over their use)
        float n0 = NANF, n1 = NANF;
        if (zdx && (t + 2) < TT) { n0 = xp0[DX]; n1 = xp1[DX]; }

        // W1: finish batch0 step t  ||  start batch1 step t
        m2_role(0, zf0, q0, op0);
        m1_role(1);
        lds_barrier();

        // W2: finish batch1 step t  ||  start batch0 step t+1
        m2_role(1, zf1, q1, op1);
        m1_role(0);                 // at t=TT-1 this is dead work, harmless
        lds_barrier();

        q0 = n0; q1 = n1;
        xp0 += DX; xp1 += DX;
        op0 += DX; op1 += DX;
    }
}

extern "C" void kernel_launch(void* const* d_in, const int* in_sizes, int n_in,
                              void* d_out, int out_size, void* d_ws, size_t ws_size,
                              hipStream_t stream) {
    const float* X  = (const float*)d_in[0];
    const float* A  = (const float*)d_in[1];
    const float* W1 = (const float*)d_in[2];
    const float* W2 = (const float*)d_in[3];
    const float* h1 = (const float*)d_in[4];
    const float* h2 = (const float*)d_in[5];
    float* out = (float*)d_out;

    plrnn_scan<<<BB / 2, 512, 0, stream>>>(X, A, W1, W2, h1, h2, out);
}

// Round 12
// 800.827 us; speedup vs baseline: 1.4655x; 1.4655x over previous
//
#include <hip/hip_runtime.h>

#define BB 512
#define TT 1024
#define DX 32
#define DZ 64
#define DY 256
#define ALPHA 0.125f
#define HP 36  // hid chunk stride: 32 floats + 4 pad (8 distinct bank-quads)

typedef float v2f __attribute__((ext_vector_type(2)));

// Packed dual-FP32 FMA (full-rate on gfx950; plain v_fma_f32 is half-rate).
__device__ __forceinline__ v2f pk_fma(v2f a, v2f b, v2f c) {
    asm("v_pk_fma_f32 %0, %1, %2, %0" : "+v"(c) : "v"(a), "v"(b));
    return c;
}

// DPP add: x + dpp_permuted(x). 0xB1 xor1 | 0x4E xor2 | 0x141 row_half_mirror.
template<int CTRL>
__device__ __forceinline__ float dpp_add(float x) {
    int p = __builtin_amdgcn_update_dpp(0, __float_as_int(x), CTRL, 0xF, 0xF, true);
    return x + __int_as_float(p);
}

// R12 = R6 (best, 799us) + one-time phase-desync of odd blocks.
// Ledger: not LDS-BW (R4), not FMA issue (R6), not load depth (R7/8), not
// vmcnt drain (R9), not weight residency (R10: unified-RF kept them in
// AGPRs all along), and 1-block/CU fusion is strictly worse (R2/R11:
// 1320-1375 cy/batch-step vs 936 at 2 blocks/CU).
// Remaining hypothesis for wall = 2x chain: the two co-resident blocks'
// barrier cadences are PHASE-ALIGNED (they launch together with identical
// periods), so both blocks burst and stall simultaneously -- the stall
// windows are dead. Alignment is metastable: a one-time ~300cy s_sleep in
// odd blocks shifts their cadence half a phase, letting block B's issue
// fill block A's stall windows permanently. If this is flat, the per-CU
// serial floor is real -> roofline.
// m1: thread (y=tid>>1, h=tid&1): hidden row y over z-chunk 32h..+31; xor1.
// m2: thread (z=tid>>3, oct=tid&7): latent row z over y-chunk 32*oct..+31;
//     xor1+xor2+half_mirror; update replicated per oct-group, oct==0 stores.
__global__ __launch_bounds__(512, 4)
void plrnn_scan(const float* __restrict__ X, const float* __restrict__ A,
                const float* __restrict__ W1, const float* __restrict__ W2,
                const float* __restrict__ h1, const float* __restrict__ h2,
                float* __restrict__ out) {
    const int b   = blockIdx.x;
    const int tid = threadIdx.x;

    const int y   = tid >> 1;      // m1 output row 0..255
    const int h   = tid & 1;       // m1 z-chunk
    const int z   = tid >> 3;      // m2 output row 0..63
    const int oct = tid & 7;       // m2 y-chunk
    const int wv  = tid >> 6;      // wave id 0..7

    __shared__ float zf_s[DZ];
    __shared__ float hid_s[8 * HP];

    // ---- one-time: weight tiles into v2f pairs (32 + 32 floats) ----
    v2f w2p[16];   // pairs of W2[y][32h + ...]
    v2f w1p[16];   // pairs of W1[z][32*oct + ...]
#pragma unroll
    for (int j = 0; j < 8; ++j) {
        float4 t2 = *(const float4*)&W2[y * DZ + 32 * h + 4 * j];
        float4 t1 = *(const float4*)&W1[z * DY + 32 * oct + 4 * j];
        w2p[2 * j]     = v2f{t2.x, t2.y};
        w2p[2 * j + 1] = v2f{t2.z, t2.w};
        w1p[2 * j]     = v2f{t1.x, t1.y};
        w1p[2 * j + 1] = v2f{t1.z, t1.w};
    }
    const float h2i = (h == 0) ? h2[y] : 0.0f;    // bias folded into acc init
    const float h1i = (oct == 0) ? h1[z] : 0.0f;
    const float Ar  = A[z];
    const bool  zdx = (z < DX);    // wave-uniform (waves 0-3)

    const float* Xb = X   + (size_t)b * TT * DX;
    float*       op = out + (size_t)b * TT * DX + z;
    const float* xq = Xb + DX + z;                 // X[t+1][z] stream
    const float NANF = __int_as_float(0x7fc00000);

    // ---- zf_0 = x0 (non-NaN) on first DX dims, else 0 (oct-replicated) ----
    float zfreg = 0.0f;
    if (zdx) { float x0 = Xb[z]; zfreg = (x0 == x0) ? x0 : 0.0f; }
    if (oct == 0) zf_s[z] = zfreg;
    __syncthreads();

    // ---- PHASE DESYNC: odd blocks sleep ~half a step-period once. ----
    // s_sleep(N) idles the wave ~N*64 cycles; 5*64=320cy ~ half of the
    // ~900cy phase chain. The barrier loop preserves the offset after.
    if (blockIdx.x & 1) __builtin_amdgcn_s_sleep(5);

    const int hidx = wv * HP + (y & 31);   // m1 write slot (h==0 lanes)

    for (int t = 0; t < TT; ++t) {
        // prefetch next forcing value (consumed at the m2 tail)
        float xnext = NANF;
        if (zdx && (t + 1) < TT) xnext = xq[0];
        xq += DX;

        // ---- m1: hidden = relu(W2 @ zf + h2) ----
        float4 zl4[8];
        {
            const float4* zp = (const float4*)(zf_s + 32 * h);
#pragma unroll
            for (int j = 0; j < 8; ++j) zl4[j] = zp[j];
        }
        v2f accA = {h2i, 0.f}, accB = {0.f, 0.f};
#pragma unroll
        for (int j = 0; j < 8; ++j) {
            accA = pk_fma(w2p[2 * j],     v2f{zl4[j].x, zl4[j].y}, accA);
            accB = pk_fma(w2p[2 * j + 1], v2f{zl4[j].z, zl4[j].w}, accB);
        }
        float d1 = (accA[0] + accB[0]) + (accA[1] + accB[1]);
        d1 = dpp_add<0xB1>(d1);                     // join the two z-halves
        if (h == 0) hid_s[hidx] = fmaxf(d1, 0.0f);
        __syncthreads();

        // ---- m2 + fused update: z_new = A*zf + W1 @ hidden + h1 ----
        float4 hl4[8];
        {
            const float4* hp = (const float4*)(hid_s + HP * oct);
#pragma unroll
            for (int j = 0; j < 8; ++j) hl4[j] = hp[j];
        }
        v2f acA = {h1i, 0.f}, acB = {0.f, 0.f};
#pragma unroll
        for (int j = 0; j < 8; ++j) {
            acA = pk_fma(w1p[2 * j],     v2f{hl4[j].x, hl4[j].y}, acA);
            acB = pk_fma(w1p[2 * j + 1], v2f{hl4[j].z, hl4[j].w}, acB);
        }
        float d2 = (acA[0] + acB[0]) + (acA[1] + acB[1]);
        d2 = dpp_add<0xB1>(d2);
        d2 = dpp_add<0x4E>(d2);
        d2 = dpp_add<0x141>(d2);                    // full 8-oct sum, all lanes

        float zn = fmaf(Ar, zfreg, d2);
        if (zdx) {                                  // wave-uniform branch
            if (oct == 0) *op = zn;
            zfreg = (xnext == xnext) ? fmaf(ALPHA, xnext, 0.875f * zn) : zn;
        } else {
            zfreg = zn;
        }
        if (oct == 0) zf_s[z] = zfreg;
        op += DX;
        __syncthreads();
    }
}

extern "C" void kernel_launch(void* const* d_in, const int* in_sizes, int n_in,
                              void* d_out, int out_size, void* d_ws, size_t ws_size,
                              hipStream_t stream) {
    const float* X  = (const float*)d_in[0];
    const float* A  = (const float*)d_in[1];
    const float* W1 = (const float*)d_in[2];
    const float* W2 = (const float*)d_in[3];
    const float* h1 = (const float*)d_in[4];
    const float* h2 = (const float*)d_in[5];
    float* out = (float*)d_out;

    plrnn_scan<<<BB, 512, 0, stream>>>(X, A, W1, W2, h1, h2, out);
}